// Round 8
// baseline (242.321 us; speedup 1.0000x reference)
//
#include <hip/hip_runtime.h>
#include <hip/hip_bf16.h>

typedef unsigned short u16;
typedef __attribute__((ext_vector_type(8))) short s16x8;
typedef __attribute__((ext_vector_type(4))) float f32x4;
typedef __attribute__((address_space(3))) u16 lds_u16;
typedef __attribute__((address_space(1))) const u16 g_u16;

#define CIN 256
#define COUT 256
#define NPIX 3136      // 56*56
#define CWROW 168      // 336B stride
#define CWPB (16 * COUT * CWROW)   // 688128 elems per batch
// xq layout: [b][ck(16)][h'(58)][hf(2)][w'(58)][ci8(8)] bf16 — ci halves contiguous over w'.
// cw layout: [b][ck(16)][o(256)][t(10)+pad][ci(16)] bf16, t=9 zero pad, 160..167 dead pad.
// parts layout: [hg(7)][b(16)][c(256)] f32 raw GAP partial sums.

__device__ __forceinline__ u16 f2b(float f) {   // f32 -> bf16 bits, RNE
  union { float f; unsigned u; } c; c.f = f;
  unsigned r = (c.u + 0x7FFFu + ((c.u >> 16) & 1u)) >> 16;
  return (u16)r;
}

// ---------------- K0: transpose x -> xq + fused GAP — r7 VERBATIM (proven) ----------------
__global__ __launch_bounds__(256)
void transpose_gap_kernel(const float* __restrict__ x, u16* __restrict__ xq,
                          float* __restrict__ parts) {
  const int hg = blockIdx.x, ck = blockIdx.y, b = blockIdx.z;
  const int tid = threadIdx.x;
  const int ci = tid >> 4, sub = tid & 15;
  __shared__ __align__(16) u16 tile[928 * 8];   // 14,848 B

  if (tid < 32) {                 // zero w'-halo units: (row, hf) x wp in {0,57}
    int r = tid >> 2, hf = (tid >> 1) & 1, wp = (tid & 1) * 57;
    int u = (r * 2 + hf) * 58 + wp;
    int us = u ^ ((u >> 3) & 7);
    *(uint4*)&tile[us * 8] = (uint4){0, 0, 0, 0};
  }
  const float* src = x + ((size_t)(b * CIN + ck * 16 + ci) * NPIX + (size_t)hg * 448);
  float s = 0.f;
#pragma unroll
  for (int it = 0; it < 7; ++it) {
    int p = it * 16 + sub;                      // [0,112): 8 rows x 14 float4
    int row = p / 14, wq = p - row * 14;
    float4 v = *(const float4*)(src + p * 4);
    s += v.x + v.y + v.z + v.w;
    u16 q[4] = { f2b(v.x), f2b(v.y), f2b(v.z), f2b(v.w) };
#pragma unroll
    for (int k = 0; k < 4; ++k) {
      int wp = wq * 4 + 1 + k;                  // w' in [1,56]
      int u = (row * 2 + (ci >> 3)) * 58 + wp;  // half-major, w'-minor unit index
      int us = u ^ ((u >> 3) & 7);
      tile[us * 8 + (ci & 7)] = q[k];
    }
  }
  for (int off = 8; off; off >>= 1) s += __shfl_down(s, off, 16);  // 16 lanes share ci
  if (sub == 0) parts[(hg * 16 + b) * 256 + ck * 16 + ci] = s;     // plain store
  __syncthreads();
  uint4* dst = (uint4*)(xq + ((size_t)(b * 16 + ck) * 58 + hg * 8 + 1) * 928);
  for (int idx = tid; idx < 928; idx += 256) {  // 8 rows x 116 uint4, contiguous
    int us = idx ^ ((idx >> 3) & 7);
    dst[idx] = *(const uint4*)&tile[us * 8];
  }
  if (hg == 0 && tid < 116)                     // halo row h'=0
    ((uint4*)(xq + ((size_t)(b * 16 + ck) * 58) * 928))[tid] = (uint4){0, 0, 0, 0};
  if (hg == 6 && tid < 116)                     // halo row h'=57
    ((uint4*)(xq + ((size_t)(b * 16 + ck) * 58 + 57) * 928))[tid] = (uint4){0, 0, 0, 0};
}

// ---------------- K3: combine — r4/r6 VERBATIM (parts pre-reduce, LDS-staged stores) -------------
__global__ __launch_bounds__(256)
void combine_kernel(const float* __restrict__ W, const float* __restrict__ parts,
                    const float* __restrict__ rw, const float* __restrict__ rb,
                    u16* __restrict__ cw) {
  const int o = blockIdx.x, tid = threadIdx.x;
  __shared__ float pooled_lds[16 * 256];            // 16,384 B
  __shared__ float rs[128];
  __shared__ __align__(16) u16 st[2][16 * CWROW];   // 10,752 B
  for (int b = 0; b < 16; ++b) {                    // pre-reduce 7 hg-partials
    float s = 0.f;
#pragma unroll
    for (int hg = 0; hg < 7; ++hg) s += parts[(hg * 16 + b) * 256 + tid];
    pooled_lds[b * 256 + tid] = s;
  }
  for (int i = tid; i < (2 * 16 * CWROW) / 8; i += 256)   // zero staging (t=9 + pad)
    ((uint4*)st)[i] = (uint4){0, 0, 0, 0};
  __syncthreads();
  if (tid < 128) {                       // routing: r[b][e]
    int b = tid >> 3, e = tid & 7;
    float s = rb[e];
    const float* pb = pooled_lds + b * 256;
    const float* we = rw + e * CIN;
    for (int c = 0; c < CIN; ++c) s += (pb[c] * (1.f / 3136.f)) * we[c];
    rs[tid] = 1.f / (1.f + __expf(-s));
  }
  float wreg[8][9];
#pragma unroll
  for (int e = 0; e < 8; ++e) {
    const float* wp = W + ((size_t)(e * COUT + o)) * 2304 + tid;
#pragma unroll
    for (int k = 0; k < 9; ++k) wreg[e][k] = wp[k * 256];
  }
  int slot[9];
#pragma unroll
  for (int k = 0; k < 9; ++k) {
    int j = tid + k * 256, ci = j / 9, t = j - ci * 9;
    slot[k] = (ci >> 4) * CWROW + t * 16 + (ci & 15);
  }
  __syncthreads();
  for (int b = 0; b < 16; ++b) {
    u16* sb = st[b & 1];
    float rv[8];
#pragma unroll
    for (int e = 0; e < 8; ++e) rv[e] = rs[b * 8 + e];
#pragma unroll
    for (int k = 0; k < 9; ++k) {
      float a = 0.f;
#pragma unroll
      for (int e = 0; e < 8; ++e) a += rv[e] * wreg[e][k];
      sb[slot[k]] = f2b(a);
    }
    __syncthreads();
    u16* dstb = cw + (size_t)b * CWPB;
    for (int i = tid; i < 336; i += 256) {   // 16 ck x 21 uint4, each run 336B contiguous
      int ck = i / 21, q = i - ck * 21;
      *(uint4*)(dstb + ck * (256 * CWROW) + o * CWROW + q * 8) =
          *(const uint4*)(sb + ck * CWROW + q * 8);
    }
  }
}

// ---------------- K4: conv v4 — r7 pipeline, 14 waves (896 thr) for 2x TLP ----------------
// Same tile (o64 x h14), same 3-buffer counted-vmcnt schedule, same LDS (153,600 B), grid 256
// = 1 block/CU — but 14 waves (3.5/SIMD, was 1.75). Wave = (pair, half): pair owns 2 output
// rows; half splits ns (half0: ns 0-3, half1: ns 4-6) so B-frags are NOT duplicated. A-frags
// re-read per half (cheap). Staging: 50 groups = waves 0-7 x4 + waves 8-13 x3 -> vmcnt(4|3).
__global__ __launch_bounds__(896, 4)
void conv_kernel(const u16* __restrict__ xq, const u16* __restrict__ cw,
                 const float* __restrict__ bng, const float* __restrict__ bnb,
                 const float* __restrict__ bnm, const float* __restrict__ bnv,
                 float* __restrict__ out) {
  const int l = blockIdx.x;
  const int xcd = l & 7, s = l >> 3;          // 32 blocks per XCD
  const int b = 2 * xcd + (s >> 4);
  const int rem = s & 15;
  const int ob = rem >> 2, hb = rem & 3;
  const int o0 = ob * 64, h0 = hb * 14;       // 4x14 = 56 rows, exact
  const int tid = threadIdx.x;
  const int wv = tid >> 6, lane = tid & 63, quad = lane >> 4, ln = lane & 15;
  const int pair = wv >> 1, half = wv & 1;    // pair 0..6 (2 rows each), half = ns-split

  __shared__ __align__(16) u16 xs[3][14848];  // 3 x 29,696 B (16 rows x 928, exact)
  __shared__ __align__(16) u16 as_[3][10752]; // 3 x 21,504 B -> total 153,600 B

  f32x4 acc[4][4];                            // [ms][ns-slot]; half1 uses ns-slots 0..2
#pragma unroll
  for (int ms = 0; ms < 4; ++ms)
#pragma unroll
    for (int ns = 0; ns < 4; ++ns) acc[ms][ns] = (f32x4){0.f, 0.f, 0.f, 0.f};

  int bsite[4];
#pragma unroll
  for (int ns = 0; ns < 4; ++ns) {
    int nsg = half * 4 + ns;                  // global ns 0..6 (slot 3 of half1 unused)
    int pi = (nsg < 7 ? nsg : 0) * 16 + ln;
    int hr = (pi >= 56) ? 1 : 0;
    int wc = pi - hr * 56;
    bsite[ns] = (2 * pair + hr) * 928 + wc * 8;
  }
  int boffp[5];                               // ck-invariant tap offsets
#pragma unroll
  for (int tp = 0; tp < 5; ++tp) {
    int t = tp * 2 + (quad >> 1);
    int dy, dx;
    if (t < 9) { dy = t / 3; dx = t - dy * 3; } else { dy = 1; dx = 1; }  // t=9: zero weights
    boffp[tp] = dy * 928 + dx * 8 + (quad & 1) * 464;
  }
  int abase[4];
#pragma unroll
  for (int ms = 0; ms < 4; ++ms) abase[ms] = (ms * 16 + ln) * CWROW + quad * 8;

  // staging map: 50 groups (xs 0..28, as 29..49); waves 0-7: 4 groups, waves 8-13: 3.
  const int g0 = (wv < 8) ? wv * 4 : 32 + (wv - 8) * 3;

  auto STAGE = [&](int ck, int buf) {
    const u16* xsrc = xq + ((size_t)(b * 16 + ck) * 58 + h0) * 928;      // 16 rows, exact
    const u16* asrc = cw + (size_t)b * CWPB + ((size_t)ck * COUT + o0) * CWROW; // 64 o contig
#pragma unroll
    for (int i = 0; i < 4; ++i) {
      if (i < 3 || wv < 8) {
        int G = g0 + i;
        if (G < 29)
          __builtin_amdgcn_global_load_lds((g_u16*)(xsrc + G * 512 + lane * 8),
                                           (lds_u16*)(&xs[buf][G * 512]), 16, 0, 0);
        else
          __builtin_amdgcn_global_load_lds((g_u16*)(asrc + (G - 29) * 512 + lane * 8),
                                           (lds_u16*)(&as_[buf][(G - 29) * 512]), 16, 0, 0);
      }
    }
  };

  auto COMPUTE = [&](int buf) {
#pragma unroll
    for (int tp = 0; tp < 5; ++tp) {
      s16x8 af[4];
#pragma unroll
      for (int ms = 0; ms < 4; ++ms)
        af[ms] = *(const s16x8*)&as_[buf][abase[ms] + tp * 32];
#pragma unroll
      for (int ns = 0; ns < 4; ++ns) {
        if (half == 0 || ns < 3) {            // wave-uniform guard (half1: 3 ns-slots)
          s16x8 bfr = *(const s16x8*)&xs[buf][bsite[ns] + boffp[tp]];
#pragma unroll
          for (int ms = 0; ms < 4; ++ms)
            acc[ms][ns] = __builtin_amdgcn_mfma_f32_16x16x32_bf16(af[ms], bfr, acc[ms][ns],
                                                                  0, 0, 0);
        }
      }
    }
  };

  STAGE(0, 0);
  STAGE(1, 1);
  // Window: counted drain (stage ck done, stage ck+1 still flying), barrier, issue ck+2, compute.
#define CONV_WINDOW(CK, BUF, SBUF, DO_STAGE, LAST)                                  \
  {                                                                                 \
    if (LAST)            asm volatile("s_waitcnt vmcnt(0)" ::: "memory");           \
    else if (wv < 8)     asm volatile("s_waitcnt vmcnt(4)" ::: "memory");           \
    else                 asm volatile("s_waitcnt vmcnt(3)" ::: "memory");           \
    __builtin_amdgcn_sched_barrier(0);                                              \
    __builtin_amdgcn_s_barrier();                                                   \
    __builtin_amdgcn_sched_barrier(0);                                              \
    if (DO_STAGE) STAGE((CK) + 2, SBUF);                                            \
    __builtin_amdgcn_s_setprio(1);                                                  \
    COMPUTE(BUF);                                                                   \
    __builtin_amdgcn_s_setprio(0);                                                  \
  }
  for (int jj = 0; jj < 5; ++jj) {            // windows ck=0..14 (buf indices static per slot)
    int ck = jj * 3;
    CONV_WINDOW(ck,     0, 2, true,      false);
    CONV_WINDOW(ck + 1, 1, 0, true,      false);
    CONV_WINDOW(ck + 2, 2, 1, (jj < 4),  false);
  }
  CONV_WINDOW(15, 0, 0, false, true);         // final window: full drain
#undef CONV_WINDOW

  // ---- epilogue: BN + SiLU, f32 store ----
#pragma unroll
  for (int ms = 0; ms < 4; ++ms) {
#pragma unroll
    for (int rr = 0; rr < 4; ++rr) {
      int o = o0 + ms * 16 + quad * 4 + rr;     // C/D: row = quad*4 + reg
      float inv = bng[o] * rsqrtf(bnv[o] + 1e-5f);
      float bias = bnb[o] - bnm[o] * inv;
      float* obp = out + ((size_t)(b * COUT + o)) * NPIX;
#pragma unroll
      for (int ns = 0; ns < 4; ++ns) {
        if (half == 0 || ns < 3) {
          int pi = (half * 4 + ns) * 16 + ln;   // C/D: col = lane&15
          int hr = (pi >= 56) ? 1 : 0;
          int wc = pi - hr * 56;
          int hg = h0 + 2 * pair + hr;
          float v = acc[ms][ns][rr] * inv + bias;
          v = v / (1.f + __expf(-v));           // SiLU
          obp[hg * 56 + wc] = v;
        }
      }
    }
  }
}

extern "C" void kernel_launch(void* const* d_in, const int* in_sizes, int n_in,
                              void* d_out, int out_size, void* d_ws, size_t ws_size,
                              hipStream_t stream) {
  const float* x   = (const float*)d_in[0];
  const float* rw  = (const float*)d_in[1];
  const float* rb  = (const float*)d_in[2];
  const float* W   = (const float*)d_in[3];
  const float* bng = (const float*)d_in[4];
  const float* bnb = (const float*)d_in[5];
  const float* bnm = (const float*)d_in[6];
  const float* bnv = (const float*)d_in[7];
  float* out = (float*)d_out;

  char* wsb = (char*)d_ws;
  // cw: 16*16*256*168*2 = 22,020,096 B ; xq: 16*16*58*58*16*2 (+1 KiB pad) = 27,558,912 B
  // parts: 7*16*256*4 = 114,688 B   (total 49,693,696 B)
  u16*  cw    = (u16*)wsb;
  u16*  xq    = (u16*)(wsb + 22020096);
  float* parts = (float*)(wsb + 22020096 + 27558912);

  transpose_gap_kernel<<<dim3(7, 16, 16), 256, 0, stream>>>(x, xq, parts);
  combine_kernel<<<256, 256, 0, stream>>>(W, parts, rw, rb, cw);
  conv_kernel<<<dim3(256), 896, 0, stream>>>(xq, cw, bng, bnb, bnm, bnv, out);
}

// Round 9
// 220.025 us; speedup vs baseline: 1.1013x; 1.1013x over previous
//
#include <hip/hip_runtime.h>
#include <hip/hip_bf16.h>

typedef unsigned short u16;
typedef __attribute__((ext_vector_type(8))) short s16x8;
typedef __attribute__((ext_vector_type(4))) float f32x4;
typedef __attribute__((address_space(3))) u16 lds_u16;
typedef __attribute__((address_space(1))) const u16 g_u16;

#define CIN 256
#define COUT 256
#define NPIX 3136      // 56*56
#define CWROW 168      // 336B stride
#define CWPB (16 * COUT * CWROW)   // 688128 elems per batch
// xq layout: [b][ck(16)][h'(58)][hf(2)][w'(58)][ci8(8)] bf16 — ci halves contiguous over w'.
// cw layout: [b][ck(16)][o(256)][t(10)+pad][ci(16)] bf16, t=9 zero pad, 160..167 dead pad.
// parts layout: [hg(7)][b(16)][c(256)] f32 raw GAP partial sums.

__device__ __forceinline__ u16 f2b(float f) {   // f32 -> bf16 bits, RNE
  union { float f; unsigned u; } c; c.f = f;
  unsigned r = (c.u + 0x7FFFu + ((c.u >> 16) & 1u)) >> 16;
  return (u16)r;
}

// ---------------- K0: transpose x -> xq + fused GAP — r7 VERBATIM (proven) ----------------
__global__ __launch_bounds__(256)
void transpose_gap_kernel(const float* __restrict__ x, u16* __restrict__ xq,
                          float* __restrict__ parts) {
  const int hg = blockIdx.x, ck = blockIdx.y, b = blockIdx.z;
  const int tid = threadIdx.x;
  const int ci = tid >> 4, sub = tid & 15;
  __shared__ __align__(16) u16 tile[928 * 8];   // 14,848 B

  if (tid < 32) {                 // zero w'-halo units: (row, hf) x wp in {0,57}
    int r = tid >> 2, hf = (tid >> 1) & 1, wp = (tid & 1) * 57;
    int u = (r * 2 + hf) * 58 + wp;
    int us = u ^ ((u >> 3) & 7);
    *(uint4*)&tile[us * 8] = (uint4){0, 0, 0, 0};
  }
  const float* src = x + ((size_t)(b * CIN + ck * 16 + ci) * NPIX + (size_t)hg * 448);
  float s = 0.f;
#pragma unroll
  for (int it = 0; it < 7; ++it) {
    int p = it * 16 + sub;                      // [0,112): 8 rows x 14 float4
    int row = p / 14, wq = p - row * 14;
    float4 v = *(const float4*)(src + p * 4);
    s += v.x + v.y + v.z + v.w;
    u16 q[4] = { f2b(v.x), f2b(v.y), f2b(v.z), f2b(v.w) };
#pragma unroll
    for (int k = 0; k < 4; ++k) {
      int wp = wq * 4 + 1 + k;                  // w' in [1,56]
      int u = (row * 2 + (ci >> 3)) * 58 + wp;  // half-major, w'-minor unit index
      int us = u ^ ((u >> 3) & 7);
      tile[us * 8 + (ci & 7)] = q[k];
    }
  }
  for (int off = 8; off; off >>= 1) s += __shfl_down(s, off, 16);  // 16 lanes share ci
  if (sub == 0) parts[(hg * 16 + b) * 256 + ck * 16 + ci] = s;     // plain store
  __syncthreads();
  uint4* dst = (uint4*)(xq + ((size_t)(b * 16 + ck) * 58 + hg * 8 + 1) * 928);
  for (int idx = tid; idx < 928; idx += 256) {  // 8 rows x 116 uint4, contiguous
    int us = idx ^ ((idx >> 3) & 7);
    dst[idx] = *(const uint4*)&tile[us * 8];
  }
  if (hg == 0 && tid < 116)                     // halo row h'=0
    ((uint4*)(xq + ((size_t)(b * 16 + ck) * 58) * 928))[tid] = (uint4){0, 0, 0, 0};
  if (hg == 6 && tid < 116)                     // halo row h'=57
    ((uint4*)(xq + ((size_t)(b * 16 + ck) * 58 + 57) * 928))[tid] = (uint4){0, 0, 0, 0};
}

// ---------------- K3: combine — r4/r6 VERBATIM (parts pre-reduce, LDS-staged stores) -------------
__global__ __launch_bounds__(256)
void combine_kernel(const float* __restrict__ W, const float* __restrict__ parts,
                    const float* __restrict__ rw, const float* __restrict__ rb,
                    u16* __restrict__ cw) {
  const int o = blockIdx.x, tid = threadIdx.x;
  __shared__ float pooled_lds[16 * 256];            // 16,384 B
  __shared__ float rs[128];
  __shared__ __align__(16) u16 st[2][16 * CWROW];   // 10,752 B
  for (int b = 0; b < 16; ++b) {                    // pre-reduce 7 hg-partials
    float s = 0.f;
#pragma unroll
    for (int hg = 0; hg < 7; ++hg) s += parts[(hg * 16 + b) * 256 + tid];
    pooled_lds[b * 256 + tid] = s;
  }
  for (int i = tid; i < (2 * 16 * CWROW) / 8; i += 256)   // zero staging (t=9 + pad)
    ((uint4*)st)[i] = (uint4){0, 0, 0, 0};
  __syncthreads();
  if (tid < 128) {                       // routing: r[b][e]
    int b = tid >> 3, e = tid & 7;
    float s = rb[e];
    const float* pb = pooled_lds + b * 256;
    const float* we = rw + e * CIN;
    for (int c = 0; c < CIN; ++c) s += (pb[c] * (1.f / 3136.f)) * we[c];
    rs[tid] = 1.f / (1.f + __expf(-s));
  }
  float wreg[8][9];
#pragma unroll
  for (int e = 0; e < 8; ++e) {
    const float* wp = W + ((size_t)(e * COUT + o)) * 2304 + tid;
#pragma unroll
    for (int k = 0; k < 9; ++k) wreg[e][k] = wp[k * 256];
  }
  int slot[9];
#pragma unroll
  for (int k = 0; k < 9; ++k) {
    int j = tid + k * 256, ci = j / 9, t = j - ci * 9;
    slot[k] = (ci >> 4) * CWROW + t * 16 + (ci & 15);
  }
  __syncthreads();
  for (int b = 0; b < 16; ++b) {
    u16* sb = st[b & 1];
    float rv[8];
#pragma unroll
    for (int e = 0; e < 8; ++e) rv[e] = rs[b * 8 + e];
#pragma unroll
    for (int k = 0; k < 9; ++k) {
      float a = 0.f;
#pragma unroll
      for (int e = 0; e < 8; ++e) a += rv[e] * wreg[e][k];
      sb[slot[k]] = f2b(a);
    }
    __syncthreads();
    u16* dstb = cw + (size_t)b * CWPB;
    for (int i = tid; i < 336; i += 256) {   // 16 ck x 21 uint4, each run 336B contiguous
      int ck = i / 21, q = i - ck * 21;
      *(uint4*)(dstb + ck * (256 * CWROW) + o * CWROW + q * 8) =
          *(const uint4*)(sb + ck * CWROW + q * 8);
    }
  }
}

// ---------------- K4: conv v5 — 14 waves via ms-split (epilogue-safe), r7 schedule --------------
// 896 thr (14 waves), grid 256 = 1 blk/CU, same tile (o64 x h14), same 3-buffer counted-vmcnt
// pipeline, same LDS (153,600 B). Wave = (pair, half): pair owns 2 output rows (B-frags shared,
// read by both halves); half owns 2 of 4 ms sub-tiles (32 o's) -> A-frag reads split, acc 56
// f32/lane, and the EPILOGUE writes the same 224B-contiguous runs as r7 (r8's ns-split caused
// 64B partial-line writes -> +25MB WRITE +23MB RMW FETCH; this is the fix under test).
__global__ __launch_bounds__(896, 1)
void conv_kernel(const u16* __restrict__ xq, const u16* __restrict__ cw,
                 const float* __restrict__ bng, const float* __restrict__ bnb,
                 const float* __restrict__ bnm, const float* __restrict__ bnv,
                 float* __restrict__ out) {
  const int l = blockIdx.x;
  const int xcd = l & 7, s = l >> 3;          // 32 blocks per XCD
  const int b = 2 * xcd + (s >> 4);
  const int rem = s & 15;
  const int ob = rem >> 2, hb = rem & 3;
  const int o0 = ob * 64, h0 = hb * 14;       // 4x14 = 56 rows, exact
  const int tid = threadIdx.x;
  const int wv = tid >> 6, lane = tid & 63, quad = lane >> 4, ln = lane & 15;
  const int pair = wv >> 1, half = wv & 1;    // pair 0..6 (2 rows), half = ms-split (2 ms each)

  __shared__ __align__(16) u16 xs[3][14848];  // 3 x 29,696 B (16 rows x 928, exact)
  __shared__ __align__(16) u16 as_[3][10752]; // 3 x 21,504 B -> total 153,600 B

  f32x4 acc[2][7];                            // [ms-slot][ns]
#pragma unroll
  for (int ms = 0; ms < 2; ++ms)
#pragma unroll
    for (int ns = 0; ns < 7; ++ns) acc[ms][ns] = (f32x4){0.f, 0.f, 0.f, 0.f};

  int bsite[7];
#pragma unroll
  for (int ns = 0; ns < 7; ++ns) {            // pair owns out-rows 2*pair, 2*pair+1 (of 14)
    int pi = ns * 16 + ln;
    int hr = (pi >= 56) ? 1 : 0;
    int wc = pi - hr * 56;
    bsite[ns] = (2 * pair + hr) * 928 + wc * 8;
  }
  int boffp[5];                               // ck-invariant tap offsets
#pragma unroll
  for (int tp = 0; tp < 5; ++tp) {
    int t = tp * 2 + (quad >> 1);
    int dy, dx;
    if (t < 9) { dy = t / 3; dx = t - dy * 3; } else { dy = 1; dx = 1; }  // t=9: zero weights
    boffp[tp] = dy * 928 + dx * 8 + (quad & 1) * 464;
  }
  int abase[2];
#pragma unroll
  for (int ms = 0; ms < 2; ++ms)              // global o-row = (half*2+ms)*16 + ln
    abase[ms] = ((half * 2 + ms) * 16 + ln) * CWROW + quad * 8;

  // staging map: 50 groups (xs 0..28, as 29..49); waves 0-7: 4 groups, waves 8-13: 3.
  const int g0 = (wv < 8) ? wv * 4 : 32 + (wv - 8) * 3;

  auto STAGE = [&](int ck, int buf) {
    const u16* xsrc = xq + ((size_t)(b * 16 + ck) * 58 + h0) * 928;      // 16 rows, exact
    const u16* asrc = cw + (size_t)b * CWPB + ((size_t)ck * COUT + o0) * CWROW; // 64 o contig
#pragma unroll
    for (int i = 0; i < 4; ++i) {
      if (i < 3 || wv < 8) {
        int G = g0 + i;
        if (G < 29)
          __builtin_amdgcn_global_load_lds((g_u16*)(xsrc + G * 512 + lane * 8),
                                           (lds_u16*)(&xs[buf][G * 512]), 16, 0, 0);
        else
          __builtin_amdgcn_global_load_lds((g_u16*)(asrc + (G - 29) * 512 + lane * 8),
                                           (lds_u16*)(&as_[buf][(G - 29) * 512]), 16, 0, 0);
      }
    }
  };

  auto COMPUTE = [&](int buf) {
#pragma unroll
    for (int tp = 0; tp < 5; ++tp) {
      s16x8 af[2];
#pragma unroll
      for (int ms = 0; ms < 2; ++ms)
        af[ms] = *(const s16x8*)&as_[buf][abase[ms] + tp * 32];
#pragma unroll
      for (int ns = 0; ns < 7; ++ns) {
        s16x8 bfr = *(const s16x8*)&xs[buf][bsite[ns] + boffp[tp]];
#pragma unroll
        for (int ms = 0; ms < 2; ++ms)
          acc[ms][ns] = __builtin_amdgcn_mfma_f32_16x16x32_bf16(af[ms], bfr, acc[ms][ns],
                                                                0, 0, 0);
      }
    }
  };

  STAGE(0, 0);
  STAGE(1, 1);
  // Window: counted drain (stage ck done, stage ck+1 still flying), barrier, issue ck+2, compute.
#define CONV_WINDOW(CK, BUF, SBUF, DO_STAGE, LAST)                                  \
  {                                                                                 \
    if (LAST)            asm volatile("s_waitcnt vmcnt(0)" ::: "memory");           \
    else if (wv < 8)     asm volatile("s_waitcnt vmcnt(4)" ::: "memory");           \
    else                 asm volatile("s_waitcnt vmcnt(3)" ::: "memory");           \
    __builtin_amdgcn_sched_barrier(0);                                              \
    __builtin_amdgcn_s_barrier();                                                   \
    __builtin_amdgcn_sched_barrier(0);                                              \
    if (DO_STAGE) STAGE((CK) + 2, SBUF);                                            \
    __builtin_amdgcn_s_setprio(1);                                                  \
    COMPUTE(BUF);                                                                   \
    __builtin_amdgcn_s_setprio(0);                                                  \
  }
  for (int jj = 0; jj < 5; ++jj) {            // windows ck=0..14 (buf indices static per slot)
    int ck = jj * 3;
    CONV_WINDOW(ck,     0, 2, true,      false);
    CONV_WINDOW(ck + 1, 1, 0, true,      false);
    CONV_WINDOW(ck + 2, 2, 1, (jj < 4),  false);
  }
  CONV_WINDOW(15, 0, 0, false, true);         // final window: full drain
#undef CONV_WINDOW

  // ---- epilogue: BN + SiLU, f32 store (r7 pattern: 224B contiguous runs per (o,row)) ----
#pragma unroll
  for (int ms = 0; ms < 2; ++ms) {
#pragma unroll
    for (int rr = 0; rr < 4; ++rr) {
      int o = o0 + (half * 2 + ms) * 16 + quad * 4 + rr;   // C/D: row = quad*4 + reg
      float inv = bng[o] * rsqrtf(bnv[o] + 1e-5f);
      float bias = bnb[o] - bnm[o] * inv;
      float* obp = out + ((size_t)(b * COUT + o)) * NPIX;
#pragma unroll
      for (int ns = 0; ns < 7; ++ns) {
        int pi = ns * 16 + ln;                  // C/D: col = lane&15
        int hr = (pi >= 56) ? 1 : 0;
        int wc = pi - hr * 56;
        int hg = h0 + 2 * pair + hr;
        float v = acc[ms][ns][rr] * inv + bias;
        v = v / (1.f + __expf(-v));             // SiLU
        obp[hg * 56 + wc] = v;
      }
    }
  }
}

extern "C" void kernel_launch(void* const* d_in, const int* in_sizes, int n_in,
                              void* d_out, int out_size, void* d_ws, size_t ws_size,
                              hipStream_t stream) {
  const float* x   = (const float*)d_in[0];
  const float* rw  = (const float*)d_in[1];
  const float* rb  = (const float*)d_in[2];
  const float* W   = (const float*)d_in[3];
  const float* bng = (const float*)d_in[4];
  const float* bnb = (const float*)d_in[5];
  const float* bnm = (const float*)d_in[6];
  const float* bnv = (const float*)d_in[7];
  float* out = (float*)d_out;

  char* wsb = (char*)d_ws;
  // cw: 16*16*256*168*2 = 22,020,096 B ; xq: 16*16*58*58*16*2 (+1 KiB pad) = 27,558,912 B
  // parts: 7*16*256*4 = 114,688 B   (total 49,693,696 B)
  u16*  cw    = (u16*)wsb;
  u16*  xq    = (u16*)(wsb + 22020096);
  float* parts = (float*)(wsb + 22020096 + 27558912);

  transpose_gap_kernel<<<dim3(7, 16, 16), 256, 0, stream>>>(x, xq, parts);
  combine_kernel<<<256, 256, 0, stream>>>(W, parts, rw, rb, cw);
  conv_kernel<<<dim3(256), 896, 0, stream>>>(xq, cw, bng, bnb, bnm, bnv, out);
}